// Round 6
// baseline (281.793 us; speedup 1.0000x reference)
//
#include <hip/hip_runtime.h>
#include <stdint.h>
#include <math.h>

typedef __attribute__((ext_vector_type(8))) __bf16 bf16x8;
typedef __attribute__((ext_vector_type(4))) float floatx4;

// Problem constants (B=4096, C=10000, D=128)
constexpr int kB = 4096;
constexpr int kC = 10000;
constexpr int kD = 128;
constexpr int kNT = 79;                   // col tiles of 128 (C padded to 10112)
constexpr int kMT = 32;                   // row tiles of 128
constexpr int kBricksB = kNT * 32;        // 2528 bricks of 1KB each
constexpr int kBricksA = kMT * 32;        // 1024
constexpr int kPrepBlocks = (kBricksB + kBricksA) / 4;  // 888
constexpr float kPI = 3.14159265358979323846f;
constexpr float kLambda = 0.1f;
constexpr float kInvInter = (float)(1.0 / (4096.0 * 9999.0 * 3.141592653589793));

constexpr int kCEBlocks = kB / 4;          // 1024 (one row per wave, 4 waves/blk)
constexpr int kInterBlocks = kNT * kMT;    // 2528
// launch1 grid: CE blocks first (long pole, dispatched first), then prep,
// then the margins block.
constexpr int kL1Blocks = kCEBlocks + kPrepBlocks + 1;  // 1913

// Partial-sum slots in workspace (plain stores; separate finalize kernel —
// R2/R3 proved per-block coherent publish costs ~35 us of block-retire
// stalls, far more than the launch it saves).
constexpr size_t kBrickBytes = (size_t)(kBricksB + kBricksA) * 1024;  // 3,637,248
constexpr int kPartMargin = 0;            // 1 slot
constexpr int kPartCE = 1;                // 4096 slots
constexpr int kPartInter = 1 + kB;        // 2528 slots
constexpr int kNumPart = 1 + kB + kNT * kMT;  // 6625

// Branchless acos approx, abs err ~6.7e-5 (Abramowitz-Stegun 4.4.45).
__device__ __forceinline__ float fast_acos(float x) {
    float t = fabsf(x);
    float s = sqrtf(fmaxf(1.0f - t, 0.0f));
    float p = fmaf(fmaf(fmaf(-0.0187293f, t, 0.0742610f), t, -0.2121144f),
                   t, 1.5707288f);
    float r = s * p;
    return x < 0.0f ? kPI - r : r;
}

// fp32 -> bf16 round-to-nearest-even bit pattern
__device__ __forceinline__ uint16_t f2bf(float f) {
    union { float f; uint32_t u; } c; c.f = f;
    uint32_t u = c.u;
    uint32_t r = (u + 0x7FFFu + ((u >> 16) & 1u)) >> 16;
    return (uint16_t)r;
}

// ---------------------------------------------------------------------------
// launch 1: prep ∥ CE in one kernel (they are fully independent — prep writes
// the brick workspace, CE reads logits — so prep's ~5 us hides under CE's
// memory stream and one launch gap disappears).
//
// CE role (blocks [0, 1024)): one logits row per wave, 4 waves/block, no LDS,
// no __syncthreads.  2-deep chunk double-buffer: chunk c+1's 13 nt-loads are
// issued before chunk c is consumed.  Consume order unchanged -> bit-identical
// sum.  Non-temporal: stream-once data.  logits~N(0,1): exp can't overflow.
//
// prep role (blocks [1024, 1912)): build MFMA-fragment-bricked bf16 copies of
// W (10112x128, zero-padded) and wy = W[label] (4096x128) in workspace.
// Brick = one wave's A/B fragment for mfma_f32_16x16x32_bf16:
//   lane l holds row (rb*16 + (l&15)), k = kk*32 + (l>>4)*8 + j (j=0..7)
// Bricks ordered [tile][rb(8)][kk(4)]; 1 KB each, 16 B/lane contiguous.
//
// margins role (block 1912): lambda * mean(margins).
// ---------------------------------------------------------------------------
__global__ __launch_bounds__(256) void prep_ce_kernel(
    const float* __restrict__ logits, const float* __restrict__ W,
    const float* __restrict__ margins, const int* __restrict__ label,
    uint16_t* __restrict__ wsB, uint16_t* __restrict__ wsA,
    float* __restrict__ part) {
    int b = blockIdx.x;
    int tid = threadIdx.x;
    int wave = tid >> 6, lane = tid & 63;

    if (b < kCEBlocks) {
        // ------------------------------ ce role ------------------------------
        int row = b * 4 + wave;                  // one row per wave
        const float* lp = logits + (size_t)row * kC;
        const floatx4* lp4 = (const floatx4*)lp;
        int lbl = label[row];                    // issued early (wave-uniform)
        float z = lp[lbl];                       // hides under the stream
        float s0 = 0.0f, s1 = 0.0f, s2 = 0.0f, s3 = 0.0f;
        floatx4 v[13], w[13];
        bool hastail = lane < kC / 4 - 39 * 64;  // lanes 0..3
        floatx4 vt;

        // issue chunk 0
        #pragma unroll
        for (int k = 0; k < 13; ++k)
            v[k] = __builtin_nontemporal_load(&lp4[lane + k * 64]);
        // issue chunk 1
        #pragma unroll
        for (int k = 0; k < 13; ++k)
            w[k] = __builtin_nontemporal_load(&lp4[lane + (13 + k) * 64]);
        // consume chunk 0
        #pragma unroll
        for (int k = 0; k < 13; ++k) {
            s0 += __expf(v[k].x); s1 += __expf(v[k].y);
            s2 += __expf(v[k].z); s3 += __expf(v[k].w);
        }
        // issue chunk 2
        #pragma unroll
        for (int k = 0; k < 13; ++k)
            v[k] = __builtin_nontemporal_load(&lp4[lane + (26 + k) * 64]);
        // consume chunk 1
        #pragma unroll
        for (int k = 0; k < 13; ++k) {
            s0 += __expf(w[k].x); s1 += __expf(w[k].y);
            s2 += __expf(w[k].z); s3 += __expf(w[k].w);
        }
        // issue tail (lanes 0..3), then consume chunk 2, then tail
        if (hastail) vt = __builtin_nontemporal_load(&lp4[39 * 64 + lane]);
        #pragma unroll
        for (int k = 0; k < 13; ++k) {
            s0 += __expf(v[k].x); s1 += __expf(v[k].y);
            s2 += __expf(v[k].z); s3 += __expf(v[k].w);
        }
        if (hastail) {
            s0 += __expf(vt.x); s1 += __expf(vt.y);
            s2 += __expf(vt.z); s3 += __expf(vt.w);
        }
        float s = (s0 + s1) + (s2 + s3);
        for (int off = 32; off; off >>= 1) s += __shfl_down(s, off);
        if (lane == 0) {
            float ce = __logf(s) - z;
            float intra =
                fast_acos(fminf(fmaxf(z * (1.0f / kLambda), -1.0f), 1.0f));
            part[kPartCE + row] = ce * (1.0f / kB) + intra * (1.0f / (kB * kPI));
        }
    } else if (b < kCEBlocks + kPrepBlocks) {
        // ----------------------------- prep role -----------------------------
        int blk = b - kCEBlocks;
        int brick = blk * 4 + wave;
        bool isA = brick >= kBricksB;
        int b2 = isA ? (brick - kBricksB) : brick;
        int kk = b2 & 3;
        int rb = (b2 >> 2) & 7;
        int tile = b2 >> 5;
        int row = tile * 128 + rb * 16 + (lane & 15);
        int k = kk * 32 + (lane >> 4) * 8;
        float v[8];
        if (isA) {
            int r = label[row];  // row < 4096 always for A bricks
            const float* src = W + (size_t)r * kD + k;
            #pragma unroll
            for (int j = 0; j < 8; ++j) v[j] = src[j];
        } else if (row < kC) {
            const float* src = W + (size_t)row * kD + k;
            #pragma unroll
            for (int j = 0; j < 8; ++j) v[j] = src[j];
        } else {
            #pragma unroll
            for (int j = 0; j < 8; ++j) v[j] = 0.0f;  // pad rows (masked later)
        }
        uint4 pk;
        pk.x = (uint32_t)f2bf(v[0]) | ((uint32_t)f2bf(v[1]) << 16);
        pk.y = (uint32_t)f2bf(v[2]) | ((uint32_t)f2bf(v[3]) << 16);
        pk.z = (uint32_t)f2bf(v[4]) | ((uint32_t)f2bf(v[5]) << 16);
        pk.w = (uint32_t)f2bf(v[6]) | ((uint32_t)f2bf(v[7]) << 16);
        uint4* dst = (uint4*)(isA ? wsA : wsB);
        dst[(size_t)b2 * 64 + lane] = pk;
    } else {
        // ---------------------------- margins role ---------------------------
        float s = 0.0f;
        for (int i = tid; i < kC; i += 256) s += margins[i];
        for (int off = 32; off; off >>= 1) s += __shfl_down(s, off);
        __shared__ float p[4];
        if ((tid & 63) == 0) p[tid >> 6] = s;
        __syncthreads();
        if (tid == 0)
            part[kPartMargin] = (p[0] + p[1] + p[2] + p[3]) * (kLambda / (float)kC);
    }
}

// ---------------------------------------------------------------------------
// launch 2: inter, 128x128 output tile per block, LDS-STAGED (the R5->R6
// change).  R0..R5 showed ce+inter cost is schedule-invariant ~65 us ==
// (CE L3-resident logits ~80 MB + inter fragment re-reads 323 MB) / ~5.5 TB/s
// L3 — a shared-L3 bound.  Staging each block's A+B tile into 64 KB LDS once
// halves the fragment traffic (323 -> 162 MB: each brick now read from
// global exactly once per block instead of once per consuming wave), and in
// this isolated launch (no logits stream in L2) the 3.64 MB brick set fits
// per-XCD L2, so staging reads are mostly L2 hits.
//
// LDS layout = byte-identical brick layout (A tile 32 KB, then B tile 32 KB),
// so fragment offsets are unchanged — just LDS-relative.  Fragment reads are
// lane*16 contiguous ds_read_b128 (standard MFMA pattern, conflict-free).
// Math and summation order unchanged -> bit-identical partials.
// Epilogue: fast_acos(clamp(S)) summed (cols >= 10000 masked per-lane).
// Diagonal j==y_i terms are acos(clip(||w||^2)) = 0 -> no handling needed.
// ---------------------------------------------------------------------------
__global__ __launch_bounds__(256) void inter_kernel(
    const uint16_t* __restrict__ wsA, const uint16_t* __restrict__ wsB,
    float* __restrict__ part) {
    __shared__ uint4 lds4[4096];  // 64 KB: [0,2048)=A tile, [2048,4096)=B tile
    __shared__ float red[4];
    int ii = blockIdx.x;          // 0..2527
    int mt = ii / kNT;
    int nt = ii - mt * kNT;
    int tid = threadIdx.x;
    int wave = tid >> 6, lane = tid & 63;
    int wr = wave >> 1, wc = wave & 1;

    const uint4* gA4 = (const uint4*)((const char*)wsA + (size_t)mt * 32768);
    const uint4* gB4 = (const uint4*)((const char*)wsB + (size_t)nt * 32768);

    // Stage A tile (32 KB) then B tile (32 KB), linear copy, 16 B/thread/iter.
    #pragma unroll
    for (int it = 0; it < 8; ++it) lds4[it * 256 + tid] = gA4[it * 256 + tid];
    #pragma unroll
    for (int it = 0; it < 8; ++it)
        lds4[2048 + it * 256 + tid] = gB4[it * 256 + tid];
    __syncthreads();

    const char* lA = (const char*)lds4;
    const char* lB = (const char*)lds4 + 32768;

    floatx4 zero = {0.0f, 0.0f, 0.0f, 0.0f};
    floatx4 acc[4][4];
    #pragma unroll
    for (int i = 0; i < 4; ++i)
        #pragma unroll
        for (int jj = 0; jj < 4; ++jj) acc[i][jj] = zero;

    #pragma unroll
    for (int kk = 0; kk < 4; ++kk) {
        bf16x8 a[4], bfr[4];
        #pragma unroll
        for (int i = 0; i < 4; ++i) {
            a[i] = *(const bf16x8*)(lA + ((wr * 4 + i) * 4 + kk) * 1024 +
                                    lane * 16);
            bfr[i] = *(const bf16x8*)(lB + ((wc * 4 + i) * 4 + kk) * 1024 +
                                      lane * 16);
        }
        #pragma unroll
        for (int i = 0; i < 4; ++i)
            #pragma unroll
            for (int jj = 0; jj < 4; ++jj)
                acc[i][jj] = __builtin_amdgcn_mfma_f32_16x16x32_bf16(
                    a[i], bfr[jj], acc[i][jj], 0, 0, 0);
    }

    // Epilogue: col = nt*128 + wc*64 + jj*16 + (lane&15); rows all valid.
    float local = 0.0f;
    int col0 = nt * 128 + wc * 64 + (lane & 15);
    #pragma unroll
    for (int jj = 0; jj < 4; ++jj) {
        if (col0 + jj * 16 < kC) {
            #pragma unroll
            for (int i = 0; i < 4; ++i)
                #pragma unroll
                for (int r = 0; r < 4; ++r)
                    local += fast_acos(fminf(fmaxf(acc[i][jj][r], -1.0f), 1.0f));
        }
    }
    for (int off = 32; off; off >>= 1) local += __shfl_down(local, off);
    if (lane == 0) red[wave] = local;
    __syncthreads();
    if (tid == 0)
        part[kPartInter + ii] = (red[0] + red[1] + red[2] + red[3]) * kInvInter;
}

// ---------------------------------------------------------------------------
// finalize: one block sums all 6625 pre-scaled partials -> out[0].
// Zeroes any extra out elements (out is poisoned before each launch).
// ---------------------------------------------------------------------------
__global__ __launch_bounds__(256) void finalize_kernel(
    const float* __restrict__ part, float* __restrict__ out, int out_size) {
    float s = 0.0f;
    for (int i = threadIdx.x; i < kNumPart; i += 256) s += part[i];
    for (int off = 32; off; off >>= 1) s += __shfl_down(s, off);
    __shared__ float p[4];
    if ((threadIdx.x & 63) == 0) p[threadIdx.x >> 6] = s;
    __syncthreads();
    if (threadIdx.x == 0) out[0] = p[0] + p[1] + p[2] + p[3];
    for (int i = 1 + threadIdx.x; i < out_size; i += 256) out[i] = 0.0f;
}

extern "C" void kernel_launch(void* const* d_in, const int* in_sizes, int n_in,
                              void* d_out, int out_size, void* d_ws, size_t ws_size,
                              hipStream_t stream) {
    const float* logits = (const float*)d_in[0];
    const float* margins = (const float*)d_in[1];
    const float* W = (const float*)d_in[2];
    const int* label = (const int*)d_in[3];
    float* out = (float*)d_out;

    uint16_t* wsB = (uint16_t*)d_ws;                                  // 79*32KB
    uint16_t* wsA = (uint16_t*)((char*)d_ws + (size_t)kNT * 32768);   // 32*32KB
    float* part = (float*)((char*)d_ws + kBrickBytes);                // 6625 floats

    prep_ce_kernel<<<kL1Blocks, 256, 0, stream>>>(logits, W, margins, label,
                                                  wsB, wsA, part);
    inter_kernel<<<kInterBlocks, 256, 0, stream>>>(wsA, wsB, part);
    finalize_kernel<<<1, 256, 0, stream>>>(part, out, out_size);
}

// Round 7
// 274.893 us; speedup vs baseline: 1.0251x; 1.0251x over previous
//
#include <hip/hip_runtime.h>
#include <stdint.h>
#include <math.h>

typedef __attribute__((ext_vector_type(8))) __bf16 bf16x8;
typedef __attribute__((ext_vector_type(4))) float floatx4;

// Problem constants (B=4096, C=10000, D=128)
constexpr int kB = 4096;
constexpr int kC = 10000;
constexpr int kD = 128;
constexpr int kNT = 79;                   // col tiles of 128 (C padded to 10112)
constexpr int kMT = 32;                   // row tiles of 128
constexpr int kBricksB = kNT * 32;        // 2528 bricks of 1KB each
constexpr int kBricksA = kMT * 32;        // 1024
constexpr int kPrepBlocks = (kBricksB + kBricksA) / 4;  // 888
constexpr float kPI = 3.14159265358979323846f;
constexpr float kLambda = 0.1f;
constexpr float kInvInter = (float)(1.0 / (4096.0 * 9999.0 * 3.141592653589793));

// Mega-kernel grid: 8 XCDs x 828 blocks each (CE 4096 + inter 2528 = 6624).
constexpr int kMegaBlocks = kB + kNT * kMT;  // 6624 = 8 * 828
constexpr int kPerXcd = kMegaBlocks / 8;     // 828

// Partial-sum slots in workspace (no cross-block atomics; finalize sums them).
constexpr size_t kBrickBytes = (size_t)(kBricksB + kBricksA) * 1024;  // 3,637,248
constexpr int kPartMargin = 0;            // 1 slot
constexpr int kPartCE = 1;                // 4096 slots
constexpr int kPartInter = 1 + kB;        // 2528 slots
constexpr int kNumPart = 1 + kB + kNT * kMT;  // 6625

// Branchless acos approx, abs err ~6.7e-5 (Abramowitz-Stegun 4.4.45).
__device__ __forceinline__ float fast_acos(float x) {
    float t = fabsf(x);
    float s = sqrtf(fmaxf(1.0f - t, 0.0f));
    float p = fmaf(fmaf(fmaf(-0.0187293f, t, 0.0742610f), t, -0.2121144f),
                   t, 1.5707288f);
    float r = s * p;
    return x < 0.0f ? kPI - r : r;
}

// fp32 -> bf16 round-to-nearest-even bit pattern
__device__ __forceinline__ uint16_t f2bf(float f) {
    union { float f; uint32_t u; } c; c.f = f;
    uint32_t u = c.u;
    uint32_t r = (u + 0x7FFFu + ((u >> 16) & 1u)) >> 16;
    return (uint16_t)r;
}

// ---------------------------------------------------------------------------
// prep: build MFMA-fragment-bricked bf16 copies of W (10112x128, zero-padded)
// and wy = W[label] (4096x128) in workspace, plus the margins reduction.
// Brick = one wave's A/B fragment for mfma_f32_16x16x32_bf16:
//   lane l holds row (rb*16 + (l&15)), k = kk*32 + (l>>4)*8 + j (j=0..7)
// Bricks ordered [tile][rb(8)][kk(4)]; 1 KB each, 16 B/lane contiguous, so
// the GEMM reads them as perfectly-coalesced global_load_dwordx4 from L2.
// ---------------------------------------------------------------------------
__global__ __launch_bounds__(256) void prep_kernel(
    const float* __restrict__ W, const float* __restrict__ margins,
    const int* __restrict__ label, uint16_t* __restrict__ wsB,
    uint16_t* __restrict__ wsA, float* __restrict__ part) {
    int blk = blockIdx.x;
    if (blk < kPrepBlocks) {
        int brick = blk * 4 + (threadIdx.x >> 6);
        int lane = threadIdx.x & 63;
        bool isA = brick >= kBricksB;
        int b2 = isA ? (brick - kBricksB) : brick;
        int kk = b2 & 3;
        int rb = (b2 >> 2) & 7;
        int tile = b2 >> 5;
        int row = tile * 128 + rb * 16 + (lane & 15);
        int k = kk * 32 + (lane >> 4) * 8;
        float v[8];
        if (isA) {
            int r = label[row];  // row < 4096 always for A bricks
            const float* src = W + (size_t)r * kD + k;
            #pragma unroll
            for (int j = 0; j < 8; ++j) v[j] = src[j];
        } else if (row < kC) {
            const float* src = W + (size_t)row * kD + k;
            #pragma unroll
            for (int j = 0; j < 8; ++j) v[j] = src[j];
        } else {
            #pragma unroll
            for (int j = 0; j < 8; ++j) v[j] = 0.0f;  // pad rows (masked in epilogue)
        }
        uint4 pk;
        pk.x = (uint32_t)f2bf(v[0]) | ((uint32_t)f2bf(v[1]) << 16);
        pk.y = (uint32_t)f2bf(v[2]) | ((uint32_t)f2bf(v[3]) << 16);
        pk.z = (uint32_t)f2bf(v[4]) | ((uint32_t)f2bf(v[5]) << 16);
        pk.w = (uint32_t)f2bf(v[6]) | ((uint32_t)f2bf(v[7]) << 16);
        uint4* dst = (uint4*)(isA ? wsA : wsB);
        dst[(size_t)b2 * 64 + lane] = pk;
    } else {
        // margins: lambda * mean(margins)
        float s = 0.0f;
        for (int i = threadIdx.x; i < kC; i += 256) s += margins[i];
        for (int off = 32; off; off >>= 1) s += __shfl_down(s, off);
        __shared__ float p[4];
        if ((threadIdx.x & 63) == 0) p[threadIdx.x >> 6] = s;
        __syncthreads();
        if (threadIdx.x == 0)
            part[kPartMargin] = (p[0] + p[1] + p[2] + p[3]) * (kLambda / (float)kC);
    }
}

// ---------------------------------------------------------------------------
// mega: XCD-pinned schedule.  blockIdx maps to XCD x = b%8 (HW round-robin),
// within-XCD sequence q = b/8 (0..827).  Each XCD owns ONE cell of a 2x4
// (mt-half x nt-quarter) partition of the 32x79 inter tile grid; CE rows are
// prefix-split per XCD and Bresenham-interleaved with the XCD's inter blocks
// so the HBM stream and MFMA overlap.  (Best measured variant: 275.3 us.)
//
// ce role: logits are stream-once -> NON-TEMPORAL loads so they don't evict
// the L2-resident bricks. Loads batched 5+4+1 for latency tolerance.
// logits~N(0,1) so exp never overflows -> plain sum, no online max.
//
// inter role (128x128 output tile): LDS-free. MFMA fragments load straight
// from the bricked (L2-resident) workspace (coalesced 16B/lane dwordx4).
// Epilogue: fast_acos(clamp(S)) summed (cols >= 10000 masked per-lane).
// Diagonal j==y_i terms are arccos(clip(||w||^2)) = 0 on both sides of the
// reference's subtraction (P(||w||^2 < 1) ~ 1e-80), so no handling needed.
// ---------------------------------------------------------------------------
__global__ __launch_bounds__(256) void mega_kernel(
    const float* __restrict__ logits, const int* __restrict__ label,
    const uint16_t* __restrict__ wsA, const uint16_t* __restrict__ wsB,
    float* __restrict__ part) {
    int b = blockIdx.x;
    int x = b & 7;            // XCD id (HW dispatches blockIdx round-robin % 8)
    int q = b >> 3;           // within-XCD sequence 0..827
    // Per-XCD CE allotment: cells with nt-width 19 (x=6,7) get 524 CE rows,
    // the rest 508.  6*508 + 2*524 = 4096.
    int nce = (x < 6) ? 508 : 524;
    int cestart = (x < 6) ? 508 * x : 3048 + 524 * (x - 6);
    int cb = (q * nce) / kPerXcd;
    bool isce = ((q + 1) * nce) / kPerXcd > cb;
    int tid = threadIdx.x;

    if (isce) {
        // ------------------------------ ce role ------------------------------
        int row = cestart + cb;
        const float* lp = logits + (size_t)row * kC;
        const floatx4* lp4 = (const floatx4*)lp;
        float s0 = 0.0f, s1 = 0.0f, s2 = 0.0f, s3 = 0.0f;
        floatx4 v[5];
        // batch 1: 5 independent nt loads in flight
        #pragma unroll
        for (int k = 0; k < 5; ++k)
            v[k] = __builtin_nontemporal_load(&lp4[tid + k * 256]);
        #pragma unroll
        for (int k = 0; k < 5; ++k) {
            s0 += __expf(v[k].x); s1 += __expf(v[k].y);
            s2 += __expf(v[k].z); s3 += __expf(v[k].w);
        }
        // batch 2: 4 more (idx 1280+tid .. 2304+tid-256)
        #pragma unroll
        for (int k = 0; k < 4; ++k)
            v[k] = __builtin_nontemporal_load(&lp4[tid + (5 + k) * 256]);
        #pragma unroll
        for (int k = 0; k < 4; ++k) {
            s0 += __expf(v[k].x); s1 += __expf(v[k].y);
            s2 += __expf(v[k].z); s3 += __expf(v[k].w);
        }
        // tail: idx 2304..2499 -> threads 0..195
        if (tid < kC / 4 - 2304) {
            floatx4 vt = __builtin_nontemporal_load(&lp4[tid + 2304]);
            s0 += __expf(vt.x); s1 += __expf(vt.y);
            s2 += __expf(vt.z); s3 += __expf(vt.w);
        }
        float s = (s0 + s1) + (s2 + s3);
        for (int off = 32; off; off >>= 1) s += __shfl_down(s, off);
        __shared__ float ss[4];
        if ((tid & 63) == 0) ss[tid >> 6] = s;
        __syncthreads();
        if (tid == 0) {
            float S = (ss[0] + ss[1]) + (ss[2] + ss[3]);
            float z = lp[label[row]];
            float ce = __logf(S) - z;
            float intra =
                fast_acos(fminf(fmaxf(z * (1.0f / kLambda), -1.0f), 1.0f));
            part[kPartCE + row] = ce * (1.0f / kB) + intra * (1.0f / (kB * kPI));
        }
    } else {
        // ----------------------------- inter role ----------------------------
        int j = q - cb;           // 0..319 (or 0..303 on x=6,7)
        int mh = x & 1;           // mt half: this XCD owns mt in [mh*16, mh*16+16)
        int nq = x >> 1;          // nt quarter: nt in [nq*20, nq*20+{20,20,20,19})
        int mt = mh * 16 + (j & 15);
        int nt = nq * 20 + (j >> 4);
        int wave = tid >> 6, lane = tid & 63;
        int wr = wave >> 1, wc = wave & 1;

        const char* gA = (const char*)wsA + (size_t)mt * 32768;
        const char* gB = (const char*)wsB + (size_t)nt * 32768;

        floatx4 zero = {0.0f, 0.0f, 0.0f, 0.0f};
        floatx4 acc[4][4];
        #pragma unroll
        for (int i = 0; i < 4; ++i)
            #pragma unroll
            for (int jj = 0; jj < 4; ++jj) acc[i][jj] = zero;

        #pragma unroll
        for (int kk = 0; kk < 4; ++kk) {
            bf16x8 a[4], bfr[4];
            #pragma unroll
            for (int i = 0; i < 4; ++i) {
                a[i] = *(const bf16x8*)(gA + ((wr * 4 + i) * 4 + kk) * 1024 +
                                        lane * 16);
                bfr[i] = *(const bf16x8*)(gB + ((wc * 4 + i) * 4 + kk) * 1024 +
                                          lane * 16);
            }
            #pragma unroll
            for (int i = 0; i < 4; ++i)
                #pragma unroll
                for (int jj = 0; jj < 4; ++jj)
                    acc[i][jj] = __builtin_amdgcn_mfma_f32_16x16x32_bf16(
                        a[i], bfr[jj], acc[i][jj], 0, 0, 0);
        }

        // Epilogue: col = nt*128 + wc*64 + jj*16 + (lane&15); rows all valid.
        float local = 0.0f;
        int col0 = nt * 128 + wc * 64 + (lane & 15);
        #pragma unroll
        for (int jj = 0; jj < 4; ++jj) {
            if (col0 + jj * 16 < kC) {
                #pragma unroll
                for (int i = 0; i < 4; ++i)
                    #pragma unroll
                    for (int r = 0; r < 4; ++r)
                        local += fast_acos(
                            fminf(fmaxf(acc[i][jj][r], -1.0f), 1.0f));
            }
        }
        for (int off = 32; off; off >>= 1) local += __shfl_down(local, off);
        __shared__ float p[4];
        if (lane == 0) p[wave] = local;
        __syncthreads();
        if (tid == 0)
            part[kPartInter + mt * kNT + nt] =
                (p[0] + p[1] + p[2] + p[3]) * kInvInter;
    }
}

// ---------------------------------------------------------------------------
// finalize: one block sums all 6625 pre-scaled partials -> out[0].
// Zeroes any extra out elements (out is poisoned before each launch).
// ---------------------------------------------------------------------------
__global__ __launch_bounds__(256) void finalize_kernel(
    const float* __restrict__ part, float* __restrict__ out, int out_size) {
    float s = 0.0f;
    for (int i = threadIdx.x; i < kNumPart; i += 256) s += part[i];
    for (int off = 32; off; off >>= 1) s += __shfl_down(s, off);
    __shared__ float p[4];
    if ((threadIdx.x & 63) == 0) p[threadIdx.x >> 6] = s;
    __syncthreads();
    if (threadIdx.x == 0) out[0] = p[0] + p[1] + p[2] + p[3];
    for (int i = 1 + threadIdx.x; i < out_size; i += 256) out[i] = 0.0f;
}

extern "C" void kernel_launch(void* const* d_in, const int* in_sizes, int n_in,
                              void* d_out, int out_size, void* d_ws, size_t ws_size,
                              hipStream_t stream) {
    const float* logits = (const float*)d_in[0];
    const float* margins = (const float*)d_in[1];
    const float* W = (const float*)d_in[2];
    const int* label = (const int*)d_in[3];
    float* out = (float*)d_out;

    uint16_t* wsB = (uint16_t*)d_ws;                                  // 79*32KB
    uint16_t* wsA = (uint16_t*)((char*)d_ws + (size_t)kNT * 32768);   // 32*32KB
    float* part = (float*)((char*)d_ws + kBrickBytes);                // 6625 floats

    prep_kernel<<<kPrepBlocks + 1, 256, 0, stream>>>(W, margins, label, wsB, wsA, part);
    mega_kernel<<<kMegaBlocks, 256, 0, stream>>>(logits, label, wsA, wsB, part);
    finalize_kernel<<<1, 256, 0, stream>>>(part, out, out_size);
}